// Round 1
// baseline (1597207.129 us; speedup 1.0000x reference)
//
#include <hip/hip_runtime.h>
#include <math.h>

#define T_TOTAL 262144
#define HID 32

// step_fn(x) = (tanh(5x)+1)/2
__device__ __forceinline__ float stepfn(float x) {
    return 0.5f * (tanhf(5.0f * x) + 1.0f);
}

// ---------------------------------------------------------------------------
// Sequential RK4 scan: one wave (64 threads). Lane j (j = lane&31) owns
// hidden unit j of both layers; weights live in registers. Cross-lane
// broadcasts/reductions go through LDS (baseline; to be replaced by DPP).
// ---------------------------------------------------------------------------
__global__ __launch_bounds__(64) void scan_kernel(
    const float* __restrict__ inputs,   // (T,5): s_snow,s_water,precp,tmean,time
    const float* __restrict__ lday,     // (T,)
    const float* __restrict__ W1, const float* __restrict__ b1,   // (4,HID),(HID)
    const float* __restrict__ W2, const float* __restrict__ b2,   // (HID,HID),(HID)
    const float* __restrict__ W3, const float* __restrict__ b3,   // (HID,5),(5)
    float* __restrict__ traj)           // (T,2) output trajectory
{
    const int lane = threadIdx.x;
    const int j = lane & (HID - 1);

    __shared__ float ls_h[HID];
    __shared__ float ls_g[HID];
    __shared__ float ls_o[8];
    __shared__ float ls_W3[HID * 5];
    __shared__ float ls_b3[5];

    // Per-lane weight columns (registers)
    float w1c[4];
#pragma unroll
    for (int i = 0; i < 4; ++i) w1c[i] = W1[i * HID + j];
    const float b1j = b1[j];
    float w2c[HID];
#pragma unroll
    for (int i = 0; i < HID; ++i) w2c[i] = W2[i * HID + j];
    const float b2j = b2[j];

    if (lane < 5) ls_b3[lane] = b3[lane];
    for (int i = lane; i < HID * 5; i += 64) ls_W3[i] = W3[i];
    __syncthreads();

    // rhs(s0,s1,p,tm,ld) -> (d0,d1); all-uniform in/out across the wave
    auto rhs = [&](float s0, float s1, float p, float tm, float ld,
                   float* d0, float* d1) {
        // layer 1: lane j computes hidden unit j
        float pre = fmaf(s0, w1c[0], fmaf(s1, w1c[1],
                    fmaf(p,  w1c[2], fmaf(tm, w1c[3], b1j))));
        float h1 = tanhf(pre);
        __syncthreads();                 // prior consumers of ls_h/ls_o done
        if (lane < HID) ls_h[j] = h1;
        __syncthreads();
        // layer 2
        float acc = b2j;
#pragma unroll
        for (int i = 0; i < HID; ++i) acc = fmaf(ls_h[i], w2c[i], acc);
        float h2 = tanhf(acc);
        if (lane < HID) ls_g[j] = h2;
        __syncthreads();
        // output layer: lanes 0..4 each reduce one output
        if (lane < 5) {
            float a = ls_b3[lane];
#pragma unroll
            for (int i = 0; i < HID; ++i)
                a = fmaf(ls_g[i], ls_W3[i * 5 + lane], a);
            ls_o[lane] = a;
        }
        __syncthreads();
        float o0 = ls_o[0], o1 = ls_o[1], o2 = ls_o[2],
              o3 = ls_o[3], o4 = ls_o[4];
        // bucket-model fluxes (uniform, computed redundantly per lane)
        float p_snow = fmaxf(sinhf(o0) * stepfn(-tm), 0.0f);
        float p_rain = fmaxf(sinhf(o1), 0.0f);
        float melt   = fmaxf(stepfn(s0) * sinhf(o2), 0.0f);
        float ss1    = stepfn(s1);
        float et     = ss1 * expf(o3) * ld;
        float q      = ss1 * expf(o4);
        *d0 = p_snow - melt;
        *d1 = p_rain + melt - et - q;
    };

    double y0 = (double)inputs[0];
    double y1 = (double)inputs[1];
    if (lane == 0) { traj[0] = (float)y0; traj[1] = (float)y1; }

    // software-prefetch pipeline for stage inputs (2 ahead)
    float pA = inputs[2], tmA = inputs[3], ldA = lday[0];          // step n
    float pB = inputs[5 + 2], tmB = inputs[5 + 3], ldB = lday[1];  // step n+1

    for (int n = 0; n < T_TOTAL - 1; ++n) {
        const int np2 = (n + 2 < T_TOTAL) ? (n + 2) : (T_TOTAL - 1);
        const float pC  = inputs[np2 * 5 + 2];
        const float tmC = inputs[np2 * 5 + 3];
        const float ldC = lday[np2];

        const float pm  = 0.5f * (pA + pB);
        const float tmm = 0.5f * (tmA + tmB);
        const float ldm = 0.5f * (ldA + ldB);

        const float fy0 = (float)y0, fy1 = (float)y1;
        float k10, k11, k20, k21, k30, k31, k40, k41;
        rhs(fy0,              fy1,              pA, tmA, ldA, &k10, &k11);
        rhs(fy0 + 0.5f * k10, fy1 + 0.5f * k11, pm, tmm, ldm, &k20, &k21);
        rhs(fy0 + 0.5f * k20, fy1 + 0.5f * k21, pm, tmm, ldm, &k30, &k31);
        rhs(fy0 + k30,        fy1 + k31,        pB, tmB, ldB, &k40, &k41);

        y0 += (1.0 / 6.0) * ((double)k10 + 2.0 * (double)k20
                           + 2.0 * (double)k30 + (double)k40);
        y1 += (1.0 / 6.0) * ((double)k11 + 2.0 * (double)k21
                           + 2.0 * (double)k31 + (double)k41);

        if (lane == 0) {
            traj[2 * (n + 1)]     = (float)y0;
            traj[2 * (n + 1) + 1] = (float)y1;
        }
        pA = pB; tmA = tmB; ldA = ldB;
        pB = pC; tmB = tmC; ldB = ldC;
    }
}

// ---------------------------------------------------------------------------
// Parallel readout: out[t] = mlp(relu-clamped state, p, tm)[4]
// ---------------------------------------------------------------------------
__global__ __launch_bounds__(256) void out_kernel(
    const float* __restrict__ inputs,
    const float* __restrict__ traj,
    const float* __restrict__ W1, const float* __restrict__ b1,
    const float* __restrict__ W2, const float* __restrict__ b2,
    const float* __restrict__ W3, const float* __restrict__ b3,
    float* __restrict__ out)
{
    __shared__ float sW1[4 * HID];
    __shared__ float sb1[HID];
    __shared__ float sW2T[HID * HID];   // transposed: sW2T[j*HID+i] = W2[i][j]
    __shared__ float sb2[HID];
    __shared__ float sw3[HID];          // W3[:,4]
    for (int i = threadIdx.x; i < 4 * HID; i += 256) sW1[i] = W1[i];
    for (int i = threadIdx.x; i < HID; i += 256) {
        sb1[i] = b1[i]; sb2[i] = b2[i]; sw3[i] = W3[i * 5 + 4];
    }
    for (int idx = threadIdx.x; idx < HID * HID; idx += 256) {
        int jj = idx >> 5, ii = idx & 31;
        sW2T[idx] = W2[ii * HID + jj];
    }
    __syncthreads();

    int t = blockIdx.x * 256 + threadIdx.x;
    if (t >= T_TOTAL) return;

    float s0 = fmaxf(traj[2 * t],     0.0f);
    float s1 = fmaxf(traj[2 * t + 1], 0.0f);
    float p  = inputs[t * 5 + 2];
    float tm = inputs[t * 5 + 3];

    float h1[HID];
#pragma unroll
    for (int jj = 0; jj < HID; ++jj) {
        float pre = fmaf(s0, sW1[jj], fmaf(s1, sW1[HID + jj],
                    fmaf(p, sW1[2 * HID + jj],
                    fmaf(tm, sW1[3 * HID + jj], sb1[jj]))));
        h1[jj] = tanhf(pre);
    }
    float o = b3[4];
#pragma unroll 4
    for (int jj = 0; jj < HID; ++jj) {
        float a = sb2[jj];
#pragma unroll
        for (int ii = 0; ii < HID; ++ii)
            a = fmaf(h1[ii], sW2T[jj * HID + ii], a);
        o = fmaf(tanhf(a), sw3[jj], o);
    }
    out[t] = o;
}

extern "C" void kernel_launch(void* const* d_in, const int* in_sizes, int n_in,
                              void* d_out, int out_size, void* d_ws, size_t ws_size,
                              hipStream_t stream) {
    (void)in_sizes; (void)n_in; (void)out_size; (void)ws_size;
    const float* inputs = (const float*)d_in[0];
    const float* lday   = (const float*)d_in[1];
    const float* W1     = (const float*)d_in[2];
    const float* b1     = (const float*)d_in[3];
    const float* W2     = (const float*)d_in[4];
    const float* b2     = (const float*)d_in[5];
    const float* W3     = (const float*)d_in[6];
    const float* b3     = (const float*)d_in[7];
    float* out  = (float*)d_out;
    float* traj = (float*)d_ws;   // T*2 floats = 2 MB

    hipLaunchKernelGGL(scan_kernel, dim3(1), dim3(64), 0, stream,
                       inputs, lday, W1, b1, W2, b2, W3, b3, traj);
    hipLaunchKernelGGL(out_kernel, dim3((T_TOTAL + 255) / 256), dim3(256), 0, stream,
                       inputs, traj, W1, b1, W2, b2, W3, b3, out);
}

// Round 2
// 520782.715 us; speedup vs baseline: 3.0669x; 3.0669x over previous
//
#include <hip/hip_runtime.h>
#include <math.h>

#define T_TOTAL 262144
#define HID 32
#define LOG2E 1.4426950408889634f

// ---- fast transcendentals (v_exp_f32 / v_rcp_f32 based) --------------------
__device__ __forceinline__ float fexp2(float x) { return __builtin_amdgcn_exp2f(x); }
__device__ __forceinline__ float frcp(float x)  { return __builtin_amdgcn_rcpf(x); }
__device__ __forceinline__ float fast_exp(float x) { return fexp2(x * LOG2E); }
__device__ __forceinline__ float fast_tanh(float x) {
    float xc = fminf(fmaxf(x, -9.0f), 9.0f);          // avoid inf/inf
    float t  = fexp2(xc * (2.0f * LOG2E));
    return (t - 1.0f) * frcp(t + 1.0f);
}
// step_fn(x) = (tanh(5x)+1)/2 = sigmoid(10x); saturates cleanly at 0/1
__device__ __forceinline__ float fast_sig10(float x) {
    return frcp(1.0f + fexp2(x * (-10.0f * LOG2E)));
}
__device__ __forceinline__ float fast_sinh(float x) {
    float t = fast_exp(x);
    return 0.5f * (t - frcp(t));
}

// ---- DPP half-wave (32-lane) all-reduce sum --------------------------------
template <int CTRL>
__device__ __forceinline__ float dpp_add(float v) {
    int t = __builtin_amdgcn_update_dpp(0, __float_as_int(v), CTRL, 0xF, 0xF, true);
    return v + __int_as_float(t);
}
// sum over lanes 0..31 (lanes 32..63 hold duplicate data), result uniform
__device__ __forceinline__ float half_wave_allsum(float x) {
    x = dpp_add<0xB1>(x);   // quad_perm [1,0,3,2]  : xor 1
    x = dpp_add<0x4E>(x);   // quad_perm [2,3,0,1]  : xor 2
    x = dpp_add<0x141>(x);  // row_half_mirror      : + other quad
    x = dpp_add<0x140>(x);  // row_mirror           : + other octet
    x = dpp_add<0x142>(x);  // row_bcast15          : lanes16-31 = 32-sum
    return __int_as_float(__builtin_amdgcn_readlane(__float_as_int(x), 31));
}

// ---------------------------------------------------------------------------
// Sequential RK4 scan: ONE wave, zero barriers (wave-lockstep LDS), weights
// in registers, DPP reductions for the 32->5 output layer.
// ---------------------------------------------------------------------------
__global__ __launch_bounds__(64) void scan_kernel(
    const float* __restrict__ inputs,   // (T,5)
    const float* __restrict__ lday,     // (T,)
    const float* __restrict__ W1, const float* __restrict__ b1,
    const float* __restrict__ W2, const float* __restrict__ b2,
    const float* __restrict__ W3, const float* __restrict__ b3,
    float* __restrict__ traj)           // (T,2)
{
    const int lane = threadIdx.x;
    const int j = lane & (HID - 1);     // both half-waves duplicate unit j

    __shared__ float4 ls_h4[HID / 4];
    float* ls_h = (float*)ls_h4;

    // per-lane weight columns / rows in registers
    float w1c[4];
#pragma unroll
    for (int i = 0; i < 4; ++i) w1c[i] = W1[i * HID + j];
    const float b1j = b1[j];
    float w2c[HID];
#pragma unroll
    for (int i = 0; i < HID; ++i) w2c[i] = W2[i * HID + j];
    const float b2j = b2[j];
    float w3r[5], b3r[5];
#pragma unroll
    for (int o = 0; o < 5; ++o) { w3r[o] = W3[j * 5 + o]; b3r[o] = b3[o]; }

    double y0 = (double)inputs[0];
    double y1 = (double)inputs[1];
    float2* traj2 = (float2*)traj;
    if (lane == 0) traj2[0] = make_float2((float)y0, (float)y1);

    // rhs: all lanes uniform in/out; ONE LDS round-trip (h1 broadcast)
    auto rhs = [&](float s0, float s1, float p, float tm, float stm, float ld,
                   float& d0, float& d1) {
        float sg0 = fast_sig10(s0);       // independent of MLP chain —
        float sg1 = fast_sig10(s1);       // overlaps the LDS wait
        float pre = fmaf(s0, w1c[0], fmaf(s1, w1c[1], b1j))
                  + fmaf(p,  w1c[2], tm * w1c[3]);
        float h1 = fast_tanh(pre);
        __builtin_amdgcn_wave_barrier();
        ls_h[j] = h1;                      // dup write (lane j & j+32): benign
        __builtin_amdgcn_wave_barrier();
        float a0 = b2j, a1 = 0.f, a2 = 0.f, a3 = 0.f;
#pragma unroll
        for (int i = 0; i < 8; ++i) {      // ds_read_b128 x8, 4-way accum
            float4 h4 = ls_h4[i];
            a0 = fmaf(h4.x, w2c[4 * i + 0], a0);
            a1 = fmaf(h4.y, w2c[4 * i + 1], a1);
            a2 = fmaf(h4.z, w2c[4 * i + 2], a2);
            a3 = fmaf(h4.w, w2c[4 * i + 3], a3);
        }
        float g = fast_tanh((a0 + a1) + (a2 + a3));
        float o0 = half_wave_allsum(g * w3r[0]) + b3r[0];
        float o1 = half_wave_allsum(g * w3r[1]) + b3r[1];
        float o2 = half_wave_allsum(g * w3r[2]) + b3r[2];
        float o3 = half_wave_allsum(g * w3r[3]) + b3r[3];
        float o4 = half_wave_allsum(g * w3r[4]) + b3r[4];
        float p_snow = fmaxf(fast_sinh(o0) * stm, 0.f);
        float p_rain = fmaxf(fast_sinh(o1), 0.f);
        float melt   = fmaxf(sg0 * fast_sinh(o2), 0.f);
        float et     = sg1 * fast_exp(o3) * ld;
        float q      = sg1 * fast_exp(o4);
        d0 = p_snow - melt;
        d1 = p_rain + melt - et - q;
    };

    // 2-ahead raw prefetch of stage inputs
    float pA = inputs[2],     tmA = inputs[3],     ldA = lday[0];
    float pB = inputs[5 + 2], tmB = inputs[5 + 3], ldB = lday[1];

    for (int n = 0; n < T_TOTAL - 1; ++n) {
        const int np2 = (n + 2 < T_TOTAL) ? (n + 2) : (T_TOTAL - 1);
        const float pC = inputs[np2 * 5 + 2];
        const float tmC = inputs[np2 * 5 + 3];
        const float ldC = lday[np2];

        const float pm  = 0.5f * (pA + pB);
        const float tmm = 0.5f * (tmA + tmB);
        const float ldm = 0.5f * (ldA + ldB);
        const float stmA = fast_sig10(-tmA);   // step_fn(-tm): state-free,
        const float stmm = fast_sig10(-tmm);   // off the y-dependency chain
        const float stmB = fast_sig10(-tmB);

        const float fy0 = (float)y0, fy1 = (float)y1;
        float k10, k11, k20, k21, k30, k31, k40, k41;
        rhs(fy0,               fy1,               pA, tmA, stmA, ldA, k10, k11);
        rhs(fy0 + 0.5f * k10,  fy1 + 0.5f * k11, pm, tmm, stmm, ldm, k20, k21);
        rhs(fy0 + 0.5f * k20,  fy1 + 0.5f * k21, pm, tmm, stmm, ldm, k30, k31);
        rhs(fy0 + k30,         fy1 + k31,        pB, tmB, stmB, ldB, k40, k41);

        y0 += (1.0 / 6.0) * ((double)k10 + 2.0 * (double)k20
                           + 2.0 * (double)k30 + (double)k40);
        y1 += (1.0 / 6.0) * ((double)k11 + 2.0 * (double)k21
                           + 2.0 * (double)k31 + (double)k41);

        if (lane == 0) traj2[n + 1] = make_float2((float)y0, (float)y1);

        pA = pB; tmA = tmB; ldA = ldB;
        pB = pC; tmB = tmC; ldB = ldC;
    }
}

// ---------------------------------------------------------------------------
// Parallel readout: out[t] = mlp(relu(state), p, tm)[4]
// ---------------------------------------------------------------------------
__global__ __launch_bounds__(256) void out_kernel(
    const float* __restrict__ inputs,
    const float* __restrict__ traj,
    const float* __restrict__ W1, const float* __restrict__ b1,
    const float* __restrict__ W2, const float* __restrict__ b2,
    const float* __restrict__ W3, const float* __restrict__ b3,
    float* __restrict__ out)
{
    __shared__ float sW1[4 * HID];
    __shared__ float sb1[HID];
    __shared__ float sW2T[HID * HID];   // sW2T[j*HID+i] = W2[i][j]
    __shared__ float sb2[HID];
    __shared__ float sw3[HID];          // W3[:,4]
    for (int i = threadIdx.x; i < 4 * HID; i += 256) sW1[i] = W1[i];
    for (int i = threadIdx.x; i < HID; i += 256) {
        sb1[i] = b1[i]; sb2[i] = b2[i]; sw3[i] = W3[i * 5 + 4];
    }
    for (int idx = threadIdx.x; idx < HID * HID; idx += 256) {
        int jj = idx >> 5, ii = idx & 31;
        sW2T[idx] = W2[ii * HID + jj];
    }
    __syncthreads();

    int t = blockIdx.x * 256 + threadIdx.x;
    if (t >= T_TOTAL) return;

    float2 st = ((const float2*)traj)[t];
    float s0 = fmaxf(st.x, 0.0f);
    float s1 = fmaxf(st.y, 0.0f);
    float p  = inputs[t * 5 + 2];
    float tm = inputs[t * 5 + 3];

    float h1[HID];
#pragma unroll
    for (int jj = 0; jj < HID; ++jj) {
        float pre = fmaf(s0, sW1[jj], fmaf(s1, sW1[HID + jj],
                    fmaf(p, sW1[2 * HID + jj],
                    fmaf(tm, sW1[3 * HID + jj], sb1[jj]))));
        h1[jj] = fast_tanh(pre);
    }
    float o = b3[4];
#pragma unroll 4
    for (int jj = 0; jj < HID; ++jj) {
        float a0 = sb2[jj], a1 = 0.f, a2 = 0.f, a3 = 0.f;
#pragma unroll
        for (int ii = 0; ii < HID; ii += 4) {
            a0 = fmaf(h1[ii + 0], sW2T[jj * HID + ii + 0], a0);
            a1 = fmaf(h1[ii + 1], sW2T[jj * HID + ii + 1], a1);
            a2 = fmaf(h1[ii + 2], sW2T[jj * HID + ii + 2], a2);
            a3 = fmaf(h1[ii + 3], sW2T[jj * HID + ii + 3], a3);
        }
        o = fmaf(fast_tanh((a0 + a1) + (a2 + a3)), sw3[jj], o);
    }
    out[t] = o;
}

extern "C" void kernel_launch(void* const* d_in, const int* in_sizes, int n_in,
                              void* d_out, int out_size, void* d_ws, size_t ws_size,
                              hipStream_t stream) {
    (void)in_sizes; (void)n_in; (void)out_size; (void)ws_size;
    const float* inputs = (const float*)d_in[0];
    const float* lday   = (const float*)d_in[1];
    const float* W1     = (const float*)d_in[2];
    const float* b1     = (const float*)d_in[3];
    const float* W2     = (const float*)d_in[4];
    const float* b2     = (const float*)d_in[5];
    const float* W3     = (const float*)d_in[6];
    const float* b3     = (const float*)d_in[7];
    float* out  = (float*)d_out;
    float* traj = (float*)d_ws;   // T*2 floats = 2 MB

    hipLaunchKernelGGL(scan_kernel, dim3(1), dim3(64), 0, stream,
                       inputs, lday, W1, b1, W2, b2, W3, b3, traj);
    hipLaunchKernelGGL(out_kernel, dim3((T_TOTAL + 255) / 256), dim3(256), 0, stream,
                       inputs, traj, W1, b1, W2, b2, W3, b3, out);
}

// Round 3
// 407013.501 us; speedup vs baseline: 3.9242x; 1.2795x over previous
//
#include <hip/hip_runtime.h>
#include <math.h>

#define T_TOTAL 262144
#define HID 32
#define LOG2E 1.4426950408889634f

// ---- fast transcendentals (v_exp_f32 / v_rcp_f32 based) --------------------
__device__ __forceinline__ float fexp2(float x) { return __builtin_amdgcn_exp2f(x); }
__device__ __forceinline__ float frcp(float x)  { return __builtin_amdgcn_rcpf(x); }
__device__ __forceinline__ float fast_exp(float x) { return fexp2(x * LOG2E); }
__device__ __forceinline__ float fast_tanh(float x) {
    float xc = fminf(fmaxf(x, -9.0f), 9.0f);
    float t  = fexp2(xc * (2.0f * LOG2E));
    return (t - 1.0f) * frcp(t + 1.0f);
}
// step_fn(x) = (tanh(5x)+1)/2 = sigmoid(10x)
__device__ __forceinline__ float fast_sig10(float x) {
    return frcp(1.0f + fexp2(x * (-10.0f * LOG2E)));
}
__device__ __forceinline__ float fast_sinh(float x) {
    float t = fast_exp(x);
    return 0.5f * (t - frcp(t));
}

// ---- DPP butterfly: per-32-lane-half allsum --------------------------------
template <int CTRL>
__device__ __forceinline__ float dpp_add(float v) {
    int t = __builtin_amdgcn_update_dpp(0, __float_as_int(v), CTRL, 0xF, 0xF, true);
    return v + __int_as_float(t);
}
// After this, lane 31 holds sum over lanes 0..31, lane 63 holds sum 32..63.
__device__ __forceinline__ float half_allsum(float x) {
    x = dpp_add<0xB1>(x);   // quad_perm xor1
    x = dpp_add<0x4E>(x);   // quad_perm xor2
    x = dpp_add<0x141>(x);  // row_half_mirror
    x = dpp_add<0x140>(x);  // row_mirror (16-lane row sums)
    x = dpp_add<0x142>(x);  // row_bcast15 (lane31 = half sum)
    return x;
}
__device__ __forceinline__ float rl(float x, int lane) {
    return __int_as_float(__builtin_amdgcn_readlane(__float_as_int(x), lane));
}

// ---------------------------------------------------------------------------
// Sequential RK4 scan: ONE wave, no LDS, no barriers. Weights in VGPRs
// (launch_bounds(64,1) gives the allocator the full register budget).
// h1 all-gather via 32x v_readlane; output layer via paired DPP reductions.
// ---------------------------------------------------------------------------
__global__ __launch_bounds__(64, 1) void scan_kernel(
    const float* __restrict__ inputs,   // (T,5)
    const float* __restrict__ lday,     // (T,)
    const float* __restrict__ W1, const float* __restrict__ b1,
    const float* __restrict__ W2, const float* __restrict__ b2,
    const float* __restrict__ W3, const float* __restrict__ b3,
    float* __restrict__ traj)           // (T,2)
{
    const int lane = threadIdx.x;
    const int j = lane & (HID - 1);     // both half-waves hold unit j

    // per-lane weight columns in registers
    float w1c[4];
#pragma unroll
    for (int i = 0; i < 4; ++i) w1c[i] = W1[i * HID + j];
    const float b1j = b1[j];
    float w2c[HID];
#pragma unroll
    for (int i = 0; i < HID; ++i) w2c[i] = W2[i * HID + j];
    const float b2j = b2[j];
    // paired output-layer weights: chain A reduces (o0 | o3), B (o1 | o4), C (o2 | -)
    const float wA = (lane < 32) ? W3[j * 5 + 0] : W3[j * 5 + 3];
    const float wB = (lane < 32) ? W3[j * 5 + 1] : W3[j * 5 + 4];
    const float wC = W3[j * 5 + 2];
    const float b30 = b3[0], b31 = b3[1], b32 = b3[2], b33 = b3[3], b34 = b3[4];

    double y0 = (double)inputs[0];
    double y1 = (double)inputs[1];
    float2* traj2 = (float2*)traj;
    if (lane == 0) traj2[0] = make_float2((float)y0, (float)y1);

    // rhs: base = p*w1c2 + tm*w1c3 + b1j (stage-constant, hoisted)
    auto rhs = [&](float s0, float s1, float base, float stm, float ld,
                   float& d0, float& d1) {
        float sg0 = fast_sig10(s0);
        float sg1 = fast_sig10(s1);
        float pre = fmaf(s1, w1c[1], fmaf(s0, w1c[0], base));
        float h1 = fast_tanh(pre);
        // layer 2: all-gather h1 via readlane (SGPR operand of the FMA)
        float a0 = b2j, a1 = 0.f, a2 = 0.f, a3 = 0.f;
#pragma unroll
        for (int i = 0; i < HID; i += 4) {
            a0 = fmaf(rl(h1, i + 0), w2c[i + 0], a0);
            a1 = fmaf(rl(h1, i + 1), w2c[i + 1], a1);
            a2 = fmaf(rl(h1, i + 2), w2c[i + 2], a2);
            a3 = fmaf(rl(h1, i + 3), w2c[i + 3], a3);
        }
        float g = fast_tanh((a0 + a1) + (a2 + a3));
        // output layer: 3 paired DPP chains for 5 outputs
        float rA = half_allsum(g * wA);
        float rB = half_allsum(g * wB);
        float rC = half_allsum(g * wC);
        float o0 = rl(rA, 31) + b30;
        float o3 = rl(rA, 63) + b33;
        float o1 = rl(rB, 31) + b31;
        float o4 = rl(rB, 63) + b34;
        float o2 = rl(rC, 31) + b32;
        // fluxes (uniform, redundantly per lane)
        float p_snow = fmaxf(fast_sinh(o0) * stm, 0.f);
        float p_rain = fmaxf(fast_sinh(o1), 0.f);
        float melt   = fmaxf(sg0 * fast_sinh(o2), 0.f);
        float et     = sg1 * fast_exp(o3) * ld;
        float q      = sg1 * fast_exp(o4);
        d0 = p_snow - melt;
        d1 = p_rain + melt - et - q;
    };

    // 2-ahead raw prefetch of stage inputs
    float pA = inputs[2],     tmA = inputs[3],     ldA = lday[0];
    float pB = inputs[5 + 2], tmB = inputs[5 + 3], ldB = lday[1];

    for (int n = 0; n < T_TOTAL - 1; ++n) {
        const int np2 = (n + 2 < T_TOTAL) ? (n + 2) : (T_TOTAL - 1);
        const float pC  = inputs[np2 * 5 + 2];
        const float tmC = inputs[np2 * 5 + 3];
        const float ldC = lday[np2];

        const float pm  = 0.5f * (pA + pB);
        const float tmm = 0.5f * (tmA + tmB);
        const float ldm = 0.5f * (ldA + ldB);
        // stage-constant pieces (off the y-dependency chain)
        const float stmA = fast_sig10(-tmA);
        const float stmm = fast_sig10(-tmm);
        const float stmB = fast_sig10(-tmB);
        const float baseA = fmaf(pA, w1c[2], fmaf(tmA, w1c[3], b1j));
        const float basem = fmaf(pm, w1c[2], fmaf(tmm, w1c[3], b1j));
        const float baseB = fmaf(pB, w1c[2], fmaf(tmB, w1c[3], b1j));

        const float fy0 = (float)y0, fy1 = (float)y1;
        float k10, k11, k20, k21, k30, k31, k40, k41;
        rhs(fy0,                   fy1,                   baseA, stmA, ldA, k10, k11);
        rhs(fmaf(0.5f, k10, fy0),  fmaf(0.5f, k11, fy1),  basem, stmm, ldm, k20, k21);
        rhs(fmaf(0.5f, k20, fy0),  fmaf(0.5f, k21, fy1),  basem, stmm, ldm, k30, k31);
        rhs(fy0 + k30,             fy1 + k31,             baseB, stmB, ldB, k40, k41);

        const float s0sum = (k10 + 2.0f * k20) + (2.0f * k30 + k40);
        const float s1sum = (k11 + 2.0f * k21) + (2.0f * k31 + k41);
        y0 += (1.0 / 6.0) * (double)s0sum;
        y1 += (1.0 / 6.0) * (double)s1sum;

        if (lane == 0) traj2[n + 1] = make_float2((float)y0, (float)y1);

        pA = pB; tmA = tmB; ldA = ldB;
        pB = pC; tmB = tmC; ldB = ldC;
    }
}

// ---------------------------------------------------------------------------
// Parallel readout: out[t] = mlp(relu(state), p, tm)[4]
// ---------------------------------------------------------------------------
__global__ __launch_bounds__(256) void out_kernel(
    const float* __restrict__ inputs,
    const float* __restrict__ traj,
    const float* __restrict__ W1, const float* __restrict__ b1,
    const float* __restrict__ W2, const float* __restrict__ b2,
    const float* __restrict__ W3, const float* __restrict__ b3,
    float* __restrict__ out)
{
    __shared__ float sW1[4 * HID];
    __shared__ float sb1[HID];
    __shared__ float sW2T[HID * HID];   // sW2T[j*HID+i] = W2[i][j]
    __shared__ float sb2[HID];
    __shared__ float sw3[HID];          // W3[:,4]
    for (int i = threadIdx.x; i < 4 * HID; i += 256) sW1[i] = W1[i];
    for (int i = threadIdx.x; i < HID; i += 256) {
        sb1[i] = b1[i]; sb2[i] = b2[i]; sw3[i] = W3[i * 5 + 4];
    }
    for (int idx = threadIdx.x; idx < HID * HID; idx += 256) {
        int jj = idx >> 5, ii = idx & 31;
        sW2T[idx] = W2[ii * HID + jj];
    }
    __syncthreads();

    int t = blockIdx.x * 256 + threadIdx.x;
    if (t >= T_TOTAL) return;

    float2 st = ((const float2*)traj)[t];
    float s0 = fmaxf(st.x, 0.0f);
    float s1 = fmaxf(st.y, 0.0f);
    float p  = inputs[t * 5 + 2];
    float tm = inputs[t * 5 + 3];

    float h1[HID];
#pragma unroll
    for (int jj = 0; jj < HID; ++jj) {
        float pre = fmaf(s0, sW1[jj], fmaf(s1, sW1[HID + jj],
                    fmaf(p, sW1[2 * HID + jj],
                    fmaf(tm, sW1[3 * HID + jj], sb1[jj]))));
        h1[jj] = fast_tanh(pre);
    }
    float o = b3[4];
#pragma unroll 4
    for (int jj = 0; jj < HID; ++jj) {
        float a0 = sb2[jj], a1 = 0.f, a2 = 0.f, a3 = 0.f;
#pragma unroll
        for (int ii = 0; ii < HID; ii += 4) {
            a0 = fmaf(h1[ii + 0], sW2T[jj * HID + ii + 0], a0);
            a1 = fmaf(h1[ii + 1], sW2T[jj * HID + ii + 1], a1);
            a2 = fmaf(h1[ii + 2], sW2T[jj * HID + ii + 2], a2);
            a3 = fmaf(h1[ii + 3], sW2T[jj * HID + ii + 3], a3);
        }
        o = fmaf(fast_tanh((a0 + a1) + (a2 + a3)), sw3[jj], o);
    }
    out[t] = o;
}

extern "C" void kernel_launch(void* const* d_in, const int* in_sizes, int n_in,
                              void* d_out, int out_size, void* d_ws, size_t ws_size,
                              hipStream_t stream) {
    (void)in_sizes; (void)n_in; (void)out_size; (void)ws_size;
    const float* inputs = (const float*)d_in[0];
    const float* lday   = (const float*)d_in[1];
    const float* W1     = (const float*)d_in[2];
    const float* b1     = (const float*)d_in[3];
    const float* W2     = (const float*)d_in[4];
    const float* b2     = (const float*)d_in[5];
    const float* W3     = (const float*)d_in[6];
    const float* b3     = (const float*)d_in[7];
    float* out  = (float*)d_out;
    float* traj = (float*)d_ws;   // T*2 floats = 2 MB

    hipLaunchKernelGGL(scan_kernel, dim3(1), dim3(64), 0, stream,
                       inputs, lday, W1, b1, W2, b2, W3, b3, traj);
    hipLaunchKernelGGL(out_kernel, dim3((T_TOTAL + 255) / 256), dim3(256), 0, stream,
                       inputs, traj, W1, b1, W2, b2, W3, b3, out);
}

// Round 4
// 367645.264 us; speedup vs baseline: 4.3444x; 1.1071x over previous
//
#include <hip/hip_runtime.h>
#include <math.h>

#define T_TOTAL 262144
#define HID 32
#define LOG2E 1.4426950408889634f

// Pin a value into a VGPR: opaque to LLVM => cannot be rematerialized by
// re-loading from global inside the loop (R3 showed VGPR_Count=32: the
// compiler was reloading W2 every rhs instead of keeping it resident).
#define PIN(x) asm volatile("" : "+v"(x))

// ---- fast transcendentals (v_exp_f32 / v_rcp_f32 based) --------------------
__device__ __forceinline__ float fexp2(float x) { return __builtin_amdgcn_exp2f(x); }
__device__ __forceinline__ float frcp(float x)  { return __builtin_amdgcn_rcpf(x); }
__device__ __forceinline__ float fast_exp(float x) { return fexp2(x * LOG2E); }
// tanh(x) = 1 - 2/(u+1), u = exp2(2*log2e*x); clamped (layer-1 preact can be big)
__device__ __forceinline__ float fast_tanh_clamp(float x) {
    float xc = fminf(fmaxf(x, -9.0f), 9.0f);
    float u  = fexp2(xc * (2.0f * LOG2E));
    return fmaf(-2.0f, frcp(u + 1.0f), 1.0f);
}
// unclamped: safe when |x| < 40 (layer-2 preact bounded by sum|W2| ~ 5)
__device__ __forceinline__ float fast_tanh_nc(float x) {
    float u = fexp2(x * (2.0f * LOG2E));
    return fmaf(-2.0f, frcp(u + 1.0f), 1.0f);
}
// step_fn(x) = sigmoid(10x) = 1/(1+exp2(-10*log2e*x)); saturates correctly
__device__ __forceinline__ float fast_sig10(float x) {
    return frcp(1.0f + fexp2(x * (-10.0f * LOG2E)));
}
__device__ __forceinline__ float fast_sinh(float x) {
    float u = fexp2(x * LOG2E);
    return fmaf(0.5f, u, -0.5f * frcp(u));
}

// ---- DPP butterfly: per-32-lane-half allsum --------------------------------
template <int CTRL>
__device__ __forceinline__ float dpp_add(float v) {
    int t = __builtin_amdgcn_update_dpp(0, __float_as_int(v), CTRL, 0xF, 0xF, true);
    return v + __int_as_float(t);
}
// After this, lane 31 holds sum over lanes 0..31, lane 63 holds sum 32..63.
__device__ __forceinline__ float half_allsum(float x) {
    x = dpp_add<0xB1>(x);   // quad_perm xor1
    x = dpp_add<0x4E>(x);   // quad_perm xor2
    x = dpp_add<0x141>(x);  // row_half_mirror
    x = dpp_add<0x140>(x);  // row_mirror (16-lane row sums)
    x = dpp_add<0x142>(x);  // row_bcast15 (lane31/63 = half sums)
    return x;
}
__device__ __forceinline__ float rl(float x, int lane) {
    return __int_as_float(__builtin_amdgcn_readlane(__float_as_int(x), lane));
}

// ---------------------------------------------------------------------------
// Sequential RK4 scan: ONE wave, no LDS, no barriers, weights PINNED in VGPRs.
// h1 all-gather via 32x v_readlane; output layer via 3 paired DPP reductions.
// ---------------------------------------------------------------------------
__global__ __launch_bounds__(64, 1) void scan_kernel(
    const float* __restrict__ inputs,   // (T,5)
    const float* __restrict__ lday,     // (T,)
    const float* __restrict__ W1, const float* __restrict__ b1,
    const float* __restrict__ W2, const float* __restrict__ b2,
    const float* __restrict__ W3, const float* __restrict__ b3,
    float* __restrict__ traj)           // (T,2)
{
    const int lane = threadIdx.x;
    const int j = lane & (HID - 1);     // both half-waves hold unit j

    // per-lane weight columns in registers — pinned so they stay resident
    float w1c[4];
#pragma unroll
    for (int i = 0; i < 4; ++i) { w1c[i] = W1[i * HID + j]; PIN(w1c[i]); }
    float b1j = b1[j]; PIN(b1j);
    float w2c[HID];
#pragma unroll
    for (int i = 0; i < HID; ++i) { w2c[i] = W2[i * HID + j]; PIN(w2c[i]); }
    float b2j = b2[j]; PIN(b2j);
    // paired output-layer weights: chain A -> (o0|o3), B -> (o1|o4), C -> (o2|-)
    float wA = (lane < 32) ? W3[j * 5 + 0] : W3[j * 5 + 3]; PIN(wA);
    float wB = (lane < 32) ? W3[j * 5 + 1] : W3[j * 5 + 4]; PIN(wB);
    float wC = W3[j * 5 + 2]; PIN(wC);
    float b30 = b3[0], b31 = b3[1], b32 = b3[2], b33 = b3[3], b34 = b3[4];
    PIN(b30); PIN(b31); PIN(b32); PIN(b33); PIN(b34);

    double y0 = (double)inputs[0];
    double y1 = (double)inputs[1];
    float2* traj2 = (float2*)traj;
    if (lane == 0) traj2[0] = make_float2((float)y0, (float)y1);

    // rhs: base = p*w1c2 + tm*w1c3 + b1j (stage-constant, hoisted)
    auto rhs = [&](float s0, float s1, float base, float stm, float ld,
                   float& d0, float& d1) {
        float sg0 = fast_sig10(s0);
        float sg1 = fast_sig10(s1);
        float pre = fmaf(s1, w1c[1], fmaf(s0, w1c[0], base));
        float h1 = fast_tanh_clamp(pre);
        // layer 2: all-gather h1 via readlane (SGPR operand of the FMA)
        float a0 = b2j, a1 = 0.f, a2 = 0.f, a3 = 0.f;
#pragma unroll
        for (int i = 0; i < HID; i += 4) {
            a0 = fmaf(rl(h1, i + 0), w2c[i + 0], a0);
            a1 = fmaf(rl(h1, i + 1), w2c[i + 1], a1);
            a2 = fmaf(rl(h1, i + 2), w2c[i + 2], a2);
            a3 = fmaf(rl(h1, i + 3), w2c[i + 3], a3);
        }
        float g = fast_tanh_nc((a0 + a1) + (a2 + a3));
        // output layer: 3 paired DPP chains for 5 outputs
        float rA = half_allsum(g * wA);
        float rB = half_allsum(g * wB);
        float rC = half_allsum(g * wC);
        float o0 = rl(rA, 31) + b30;
        float o3 = rl(rA, 63) + b33;
        float o1 = rl(rB, 31) + b31;
        float o4 = rl(rB, 63) + b34;
        float o2 = rl(rC, 31) + b32;
        // fluxes (uniform, redundantly per lane)
        float p_snow = fmaxf(fast_sinh(o0) * stm, 0.f);
        float p_rain = fmaxf(fast_sinh(o1), 0.f);
        float melt   = fmaxf(sg0 * fast_sinh(o2), 0.f);
        float eq     = sg1 * fmaf(fast_exp(o3), ld, fast_exp(o4)); // et+q
        d0 = p_snow - melt;
        d1 = (p_rain + melt) - eq;
    };

    // 2-ahead raw prefetch of stage inputs
    float pA = inputs[2],     tmA = inputs[3],     ldA = lday[0];
    float pB = inputs[5 + 2], tmB = inputs[5 + 3], ldB = lday[1];

    for (int n = 0; n < T_TOTAL - 1; ++n) {
        const int np2 = (n + 2 < T_TOTAL) ? (n + 2) : (T_TOTAL - 1);
        const float pC  = inputs[np2 * 5 + 2];
        const float tmC = inputs[np2 * 5 + 3];
        const float ldC = lday[np2];

        const float pm  = 0.5f * (pA + pB);
        const float tmm = 0.5f * (tmA + tmB);
        const float ldm = 0.5f * (ldA + ldB);
        // stage-constant pieces (off the y-dependency chain)
        const float stmA = fast_sig10(-tmA);
        const float stmm = fast_sig10(-tmm);
        const float stmB = fast_sig10(-tmB);
        const float baseA = fmaf(pA, w1c[2], fmaf(tmA, w1c[3], b1j));
        const float basem = fmaf(pm, w1c[2], fmaf(tmm, w1c[3], b1j));
        const float baseB = fmaf(pB, w1c[2], fmaf(tmB, w1c[3], b1j));

        const float fy0 = (float)y0, fy1 = (float)y1;
        float k10, k11, k20, k21, k30, k31, k40, k41;
        rhs(fy0,                  fy1,                  baseA, stmA, ldA, k10, k11);
        rhs(fmaf(0.5f, k10, fy0), fmaf(0.5f, k11, fy1), basem, stmm, ldm, k20, k21);
        rhs(fmaf(0.5f, k20, fy0), fmaf(0.5f, k21, fy1), basem, stmm, ldm, k30, k31);
        rhs(fy0 + k30,            fy1 + k31,            baseB, stmB, ldB, k40, k41);

        const float s0sum = (k10 + 2.0f * k20) + (2.0f * k30 + k40);
        const float s1sum = (k11 + 2.0f * k21) + (2.0f * k31 + k41);
        y0 += (1.0 / 6.0) * (double)s0sum;
        y1 += (1.0 / 6.0) * (double)s1sum;

        if (lane == 0) traj2[n + 1] = make_float2((float)y0, (float)y1);

        pA = pB; tmA = tmB; ldA = ldB;
        pB = pC; tmB = tmC; ldB = ldC;
    }
}

// ---------------------------------------------------------------------------
// Parallel readout: out[t] = mlp(relu(state), p, tm)[4]
// ---------------------------------------------------------------------------
__global__ __launch_bounds__(256) void out_kernel(
    const float* __restrict__ inputs,
    const float* __restrict__ traj,
    const float* __restrict__ W1, const float* __restrict__ b1,
    const float* __restrict__ W2, const float* __restrict__ b2,
    const float* __restrict__ W3, const float* __restrict__ b3,
    float* __restrict__ out)
{
    __shared__ float sW1[4 * HID];
    __shared__ float sb1[HID];
    __shared__ float sW2T[HID * HID];   // sW2T[j*HID+i] = W2[i][j]
    __shared__ float sb2[HID];
    __shared__ float sw3[HID];          // W3[:,4]
    for (int i = threadIdx.x; i < 4 * HID; i += 256) sW1[i] = W1[i];
    for (int i = threadIdx.x; i < HID; i += 256) {
        sb1[i] = b1[i]; sb2[i] = b2[i]; sw3[i] = W3[i * 5 + 4];
    }
    for (int idx = threadIdx.x; idx < HID * HID; idx += 256) {
        int jj = idx >> 5, ii = idx & 31;
        sW2T[idx] = W2[ii * HID + jj];
    }
    __syncthreads();

    int t = blockIdx.x * 256 + threadIdx.x;
    if (t >= T_TOTAL) return;

    float2 st = ((const float2*)traj)[t];
    float s0 = fmaxf(st.x, 0.0f);
    float s1 = fmaxf(st.y, 0.0f);
    float p  = inputs[t * 5 + 2];
    float tm = inputs[t * 5 + 3];

    float h1[HID];
#pragma unroll
    for (int jj = 0; jj < HID; ++jj) {
        float pre = fmaf(s0, sW1[jj], fmaf(s1, sW1[HID + jj],
                    fmaf(p, sW1[2 * HID + jj],
                    fmaf(tm, sW1[3 * HID + jj], sb1[jj]))));
        h1[jj] = fast_tanh_clamp(pre);
    }
    float o = b3[4];
#pragma unroll 4
    for (int jj = 0; jj < HID; ++jj) {
        float a0 = sb2[jj], a1 = 0.f, a2 = 0.f, a3 = 0.f;
#pragma unroll
        for (int ii = 0; ii < HID; ii += 4) {
            a0 = fmaf(h1[ii + 0], sW2T[jj * HID + ii + 0], a0);
            a1 = fmaf(h1[ii + 1], sW2T[jj * HID + ii + 1], a1);
            a2 = fmaf(h1[ii + 2], sW2T[jj * HID + ii + 2], a2);
            a3 = fmaf(h1[ii + 3], sW2T[jj * HID + ii + 3], a3);
        }
        o = fmaf(fast_tanh_nc((a0 + a1) + (a2 + a3)), sw3[jj], o);
    }
    out[t] = o;
}

extern "C" void kernel_launch(void* const* d_in, const int* in_sizes, int n_in,
                              void* d_out, int out_size, void* d_ws, size_t ws_size,
                              hipStream_t stream) {
    (void)in_sizes; (void)n_in; (void)out_size; (void)ws_size;
    const float* inputs = (const float*)d_in[0];
    const float* lday   = (const float*)d_in[1];
    const float* W1     = (const float*)d_in[2];
    const float* b1     = (const float*)d_in[3];
    const float* W2     = (const float*)d_in[4];
    const float* b2     = (const float*)d_in[5];
    const float* W3     = (const float*)d_in[6];
    const float* b3     = (const float*)d_in[7];
    float* out  = (float*)d_out;
    float* traj = (float*)d_ws;   // T*2 floats = 2 MB

    hipLaunchKernelGGL(scan_kernel, dim3(1), dim3(64), 0, stream,
                       inputs, lday, W1, b1, W2, b2, W3, b3, traj);
    hipLaunchKernelGGL(out_kernel, dim3((T_TOTAL + 255) / 256), dim3(256), 0, stream,
                       inputs, traj, W1, b1, W2, b2, W3, b3, out);
}

// Round 5
// 358225.415 us; speedup vs baseline: 4.4587x; 1.0263x over previous
//
#include <hip/hip_runtime.h>
#include <math.h>

#define T_TOTAL 262144
#define HID 32
#define LOG2E 1.4426950408889634f

#define PIN(x) asm volatile("" : "+v"(x))

typedef _Float16 f16x8 __attribute__((ext_vector_type(8)));
typedef float f32x4 __attribute__((ext_vector_type(4)));

// ---- fast transcendentals --------------------------------------------------
__device__ __forceinline__ float fexp2(float x) { return __builtin_amdgcn_exp2f(x); }
__device__ __forceinline__ float frcp(float x)  { return __builtin_amdgcn_rcpf(x); }
__device__ __forceinline__ float fast_exp(float x) { return fexp2(x * LOG2E); }
__device__ __forceinline__ float fast_tanh_clamp(float x) {
    float xc = fminf(fmaxf(x, -9.0f), 9.0f);
    float u  = fexp2(xc * (2.0f * LOG2E));
    return fmaf(-2.0f, frcp(u + 1.0f), 1.0f);
}
__device__ __forceinline__ float fast_tanh_nc(float x) {   // |x| < 40
    float u = fexp2(x * (2.0f * LOG2E));
    return fmaf(-2.0f, frcp(u + 1.0f), 1.0f);
}
__device__ __forceinline__ float fast_sig10(float x) {     // step_fn
    return frcp(1.0f + fexp2(x * (-10.0f * LOG2E)));
}
__device__ __forceinline__ float fast_sinh(float x) {
    float u = fexp2(x * LOG2E);
    return fmaf(0.5f, u, -0.5f * frcp(u));
}

// ---- DPP butterfly over 16-lane groups (cols 0..15) ------------------------
template <int CTRL>
__device__ __forceinline__ float dpp_add(float v) {
    int t = __builtin_amdgcn_update_dpp(0, __float_as_int(v), CTRL, 0xF, 0xF, true);
    return v + __int_as_float(t);
}
// Sum over each 16-lane row; result uniform in every lane (rows identical).
__device__ __forceinline__ float allsum16(float x) {
    x = dpp_add<0xB1>(x);   // quad_perm xor1
    x = dpp_add<0x4E>(x);   // quad_perm xor2
    x = dpp_add<0x141>(x);  // row_half_mirror (xor4-equivalent here)
    x = dpp_add<0x140>(x);  // row_mirror      (xor8-equivalent here)
    return x;
}

// ---------------------------------------------------------------------------
// Sequential RK4 scan, ONE wave. Layer 2 = 4x mfma_f32_16x16x32_f16 with
// W2 as hi+lo f16 fragments (16 VGPRs total -- no spill pressure).
// h1 gathered into A-layout via 8x ds_bpermute. Layer 3 = per-lane FMAs +
// 4-step DPP butterfly (result uniform in all lanes, no readlane).
// ---------------------------------------------------------------------------
__global__ __launch_bounds__(64, 1) void scan_kernel(
    const float* __restrict__ inputs,   // (T,5)
    const float* __restrict__ lday,     // (T,)
    const float* __restrict__ W1, const float* __restrict__ b1,
    const float* __restrict__ W2, const float* __restrict__ b2,
    const float* __restrict__ W3, const float* __restrict__ b3,
    float* __restrict__ traj)           // (T,2)
{
    const int lane = threadIdx.x;
    const int col  = lane & 15;         // C/B n-index
    const int quad = lane >> 4;         // 0..3
    const int j32  = lane & 31;         // layer-1 unit owned by this lane
    const int bpidx = quad << 5;        // ds_bpermute byte base: lane quad*8

    // layer-1 weights (per-lane column j32)
    float w1c0 = W1[0 * HID + j32], w1c1 = W1[1 * HID + j32];
    float w1c2 = W1[2 * HID + j32], w1c3 = W1[3 * HID + j32];
    float b1j = b1[j32];
    PIN(w1c0); PIN(w1c1); PIN(w1c2); PIN(w1c3); PIN(b1j);

    // W2 as f16 hi/lo B-fragments: B[k][n], lane holds k=quad*8+j, n=col(+16)
    f16x8 Bhi0, Blo0, Bhi1, Blo1;
#pragma unroll
    for (int jj = 0; jj < 8; ++jj) {
        float w0 = W2[(quad * 8 + jj) * HID + col];
        float w1v = W2[(quad * 8 + jj) * HID + col + 16];
        _Float16 h0 = (_Float16)w0, h1v = (_Float16)w1v;
        Bhi0[jj] = h0;  Blo0[jj] = (_Float16)(w0 - (float)h0);
        Bhi1[jj] = h1v; Blo1[jj] = (_Float16)(w1v - (float)h1v);
    }
    PIN(Bhi0); PIN(Blo0); PIN(Bhi1); PIN(Blo1);

    float b2a = b2[col], b2b = b2[col + 16];
    PIN(b2a); PIN(b2b);

    // layer-3 weights: rows col and col+16
    float w3a[5], w3b[5], b3r[5];
#pragma unroll
    for (int k = 0; k < 5; ++k) {
        w3a[k] = W3[col * 5 + k];
        w3b[k] = W3[(col + 16) * 5 + k];
        b3r[k] = b3[k];
        PIN(w3a[k]); PIN(w3b[k]); PIN(b3r[k]);
    }

    double y0 = (double)inputs[0];
    double y1 = (double)inputs[1];
    float2* traj2 = (float2*)traj;
    if (lane == 0) traj2[0] = make_float2((float)y0, (float)y1);

    auto rhs = [&](float s0, float s1, float base, float stm, float ld,
                   float& d0, float& d1) {
        float sg0 = fast_sig10(s0);
        float sg1 = fast_sig10(s1);
        // layer 1: this lane's hidden unit j32
        float pre = fmaf(s1, w1c1, fmaf(s0, w1c0, base));
        float h1 = fast_tanh_clamp(pre);
        // gather h1 into A-layout: lane needs h1[quad*8+j], j=0..7
        int hbits = __float_as_int(h1);
        f16x8 A;
#pragma unroll
        for (int jj = 0; jj < 8; ++jj) {
            int g = __builtin_amdgcn_ds_bpermute(bpidx + 4 * jj, hbits);
            A[jj] = (_Float16)__int_as_float(g);
        }
        // layer 2: 4 independent MFMAs (hi+lo f16 decomposition of W2)
        f32x4 z = {0.f, 0.f, 0.f, 0.f};
        f32x4 chi0 = __builtin_amdgcn_mfma_f32_16x16x32_f16(A, Bhi0, z, 0, 0, 0);
        f32x4 clo0 = __builtin_amdgcn_mfma_f32_16x16x32_f16(A, Blo0, z, 0, 0, 0);
        f32x4 chi1 = __builtin_amdgcn_mfma_f32_16x16x32_f16(A, Bhi1, z, 0, 0, 0);
        f32x4 clo1 = __builtin_amdgcn_mfma_f32_16x16x32_f16(A, Blo1, z, 0, 0, 0);
        // every lane now holds h2 preacts for units col and col+16
        float g0 = fast_tanh_nc((chi0[0] + clo0[0]) + b2a);
        float g1 = fast_tanh_nc((chi1[0] + clo1[0]) + b2b);
        // layer 3: per-lane partials + DPP butterfly (uniform result)
        float o0 = allsum16(fmaf(g0, w3a[0], g1 * w3b[0])) + b3r[0];
        float o1 = allsum16(fmaf(g0, w3a[1], g1 * w3b[1])) + b3r[1];
        float o2 = allsum16(fmaf(g0, w3a[2], g1 * w3b[2])) + b3r[2];
        float o3 = allsum16(fmaf(g0, w3a[3], g1 * w3b[3])) + b3r[3];
        float o4 = allsum16(fmaf(g0, w3a[4], g1 * w3b[4])) + b3r[4];
        // fluxes
        float p_snow = fmaxf(fast_sinh(o0) * stm, 0.f);
        float p_rain = fmaxf(fast_sinh(o1), 0.f);
        float melt   = fmaxf(sg0 * fast_sinh(o2), 0.f);
        float eq     = sg1 * fmaf(fast_exp(o3), ld, fast_exp(o4)); // et+q
        d0 = p_snow - melt;
        d1 = (p_rain + melt) - eq;
    };

    // pipelined stage inputs: A=step n, B=step n+1, C=raw prefetch (n+2)
    float pA = inputs[2],  tmA = inputs[3],  ldA = lday[0];
    float pB = inputs[7],  tmB = inputs[8],  ldB = lday[1];
    float stmA = fast_sig10(-tmA), stmB = fast_sig10(-tmB);
    float baseA = fmaf(pA, w1c2, fmaf(tmA, w1c3, b1j));
    float baseB = fmaf(pB, w1c2, fmaf(tmB, w1c3, b1j));
    float pC = inputs[12], tmC = inputs[13], ldC = lday[2];

    for (int n = 0; n < T_TOTAL - 1; ++n) {
        const float pm  = 0.5f * (pA + pB);
        const float tmm = 0.5f * (tmA + tmB);
        const float ldm = 0.5f * (ldA + ldB);
        const float stmm  = fast_sig10(-tmm);
        const float basem = fmaf(pm, w1c2, fmaf(tmm, w1c3, b1j));

        const float fy0 = (float)y0, fy1 = (float)y1;
        float k10, k11, k20, k21, k30, k31, k40, k41;
        rhs(fy0,                  fy1,                  baseA, stmA, ldA, k10, k11);
        rhs(fmaf(0.5f, k10, fy0), fmaf(0.5f, k11, fy1), basem, stmm, ldm, k20, k21);
        rhs(fmaf(0.5f, k20, fy0), fmaf(0.5f, k21, fy1), basem, stmm, ldm, k30, k31);
        rhs(fy0 + k30,            fy1 + k31,            baseB, stmB, ldB, k40, k41);

        const float s0sum = (k10 + 2.0f * k20) + (2.0f * k30 + k40);
        const float s1sum = (k11 + 2.0f * k21) + (2.0f * k31 + k41);
        y0 += (1.0 / 6.0) * (double)s0sum;
        y1 += (1.0 / 6.0) * (double)s1sum;

        if (lane == 0) traj2[n + 1] = make_float2((float)y0, (float)y1);

        // shift pipeline: A<=B, B<=C (derive), prefetch new C (n+3)
        pA = pB; tmA = tmB; ldA = ldB; stmA = stmB; baseA = baseB;
        stmB  = fast_sig10(-tmC);
        baseB = fmaf(pC, w1c2, fmaf(tmC, w1c3, b1j));
        pB = pC; tmB = tmC; ldB = ldC;
        const int np3 = (n + 3 < T_TOTAL) ? (n + 3) : (T_TOTAL - 1);
        pC = inputs[np3 * 5 + 2]; tmC = inputs[np3 * 5 + 3]; ldC = lday[np3];
    }
}

// ---------------------------------------------------------------------------
// Parallel readout: out[t] = mlp(relu(state), p, tm)[4]
// ---------------------------------------------------------------------------
__global__ __launch_bounds__(256) void out_kernel(
    const float* __restrict__ inputs,
    const float* __restrict__ traj,
    const float* __restrict__ W1, const float* __restrict__ b1,
    const float* __restrict__ W2, const float* __restrict__ b2,
    const float* __restrict__ W3, const float* __restrict__ b3,
    float* __restrict__ out)
{
    __shared__ float sW1[4 * HID];
    __shared__ float sb1[HID];
    __shared__ float sW2T[HID * HID];   // sW2T[j*HID+i] = W2[i][j]
    __shared__ float sb2[HID];
    __shared__ float sw3[HID];          // W3[:,4]
    for (int i = threadIdx.x; i < 4 * HID; i += 256) sW1[i] = W1[i];
    for (int i = threadIdx.x; i < HID; i += 256) {
        sb1[i] = b1[i]; sb2[i] = b2[i]; sw3[i] = W3[i * 5 + 4];
    }
    for (int idx = threadIdx.x; idx < HID * HID; idx += 256) {
        int jj = idx >> 5, ii = idx & 31;
        sW2T[idx] = W2[ii * HID + jj];
    }
    __syncthreads();

    int t = blockIdx.x * 256 + threadIdx.x;
    if (t >= T_TOTAL) return;

    float2 st = ((const float2*)traj)[t];
    float s0 = fmaxf(st.x, 0.0f);
    float s1 = fmaxf(st.y, 0.0f);
    float p  = inputs[t * 5 + 2];
    float tm = inputs[t * 5 + 3];

    float h1[HID];
#pragma unroll
    for (int jj = 0; jj < HID; ++jj) {
        float pre = fmaf(s0, sW1[jj], fmaf(s1, sW1[HID + jj],
                    fmaf(p, sW1[2 * HID + jj],
                    fmaf(tm, sW1[3 * HID + jj], sb1[jj]))));
        h1[jj] = fast_tanh_clamp(pre);
    }
    float o = b3[4];
#pragma unroll 4
    for (int jj = 0; jj < HID; ++jj) {
        float a0 = sb2[jj], a1 = 0.f, a2 = 0.f, a3 = 0.f;
#pragma unroll
        for (int ii = 0; ii < HID; ii += 4) {
            a0 = fmaf(h1[ii + 0], sW2T[jj * HID + ii + 0], a0);
            a1 = fmaf(h1[ii + 1], sW2T[jj * HID + ii + 1], a1);
            a2 = fmaf(h1[ii + 2], sW2T[jj * HID + ii + 2], a2);
            a3 = fmaf(h1[ii + 3], sW2T[jj * HID + ii + 3], a3);
        }
        o = fmaf(fast_tanh_nc((a0 + a1) + (a2 + a3)), sw3[jj], o);
    }
    out[t] = o;
}

extern "C" void kernel_launch(void* const* d_in, const int* in_sizes, int n_in,
                              void* d_out, int out_size, void* d_ws, size_t ws_size,
                              hipStream_t stream) {
    (void)in_sizes; (void)n_in; (void)out_size; (void)ws_size;
    const float* inputs = (const float*)d_in[0];
    const float* lday   = (const float*)d_in[1];
    const float* W1     = (const float*)d_in[2];
    const float* b1     = (const float*)d_in[3];
    const float* W2     = (const float*)d_in[4];
    const float* b2     = (const float*)d_in[5];
    const float* W3     = (const float*)d_in[6];
    const float* b3     = (const float*)d_in[7];
    float* out  = (float*)d_out;
    float* traj = (float*)d_ws;   // T*2 floats = 2 MB

    hipLaunchKernelGGL(scan_kernel, dim3(1), dim3(64), 0, stream,
                       inputs, lday, W1, b1, W2, b2, W3, b3, traj);
    hipLaunchKernelGGL(out_kernel, dim3((T_TOTAL + 255) / 256), dim3(256), 0, stream,
                       inputs, traj, W1, b1, W2, b2, W3, b3, out);
}

// Round 6
// 295625.415 us; speedup vs baseline: 5.4028x; 1.2118x over previous
//
#include <hip/hip_runtime.h>
#include <math.h>

#define T_TOTAL 262144
#define HID 32
#define LOG2E 1.4426950408889634f
#define NEG10LOG2E (-14.426950408889634f)
#define POS10LOG2E (14.426950408889634f)

#define PIN(x) asm volatile("" : "+v"(x))

typedef _Float16 f16x8 __attribute__((ext_vector_type(8)));
typedef float f32x4 __attribute__((ext_vector_type(4)));

// ---- fast transcendentals --------------------------------------------------
__device__ __forceinline__ float fexp2(float x) { return __builtin_amdgcn_exp2f(x); }
__device__ __forceinline__ float frcp(float x)  { return __builtin_amdgcn_rcpf(x); }
__device__ __forceinline__ float fast_tanh_clamp(float x) {
    float xc = __builtin_amdgcn_fmed3f(x, -9.0f, 9.0f);
    float u  = fexp2(xc * (2.0f * LOG2E));
    return fmaf(-2.0f, frcp(u + 1.0f), 1.0f);
}
__device__ __forceinline__ float fast_tanh_nc(float x) {   // |x| < 40
    float u = fexp2(x * (2.0f * LOG2E));
    return fmaf(-2.0f, frcp(u + 1.0f), 1.0f);
}
__device__ __forceinline__ float fast_sig10(float x) {     // init-time only
    return frcp(1.0f + fexp2(x * NEG10LOG2E));
}

// ---- DPP helpers -----------------------------------------------------------
template <int CTRL>
__device__ __forceinline__ float dpp_add(float v) {
    int t = __builtin_amdgcn_update_dpp(0, __float_as_int(v), CTRL, 0xF, 0xF, true);
    return v + __int_as_float(t);
}
// Sum within each 16-lane row; every lane of the row gets the row sum.
__device__ __forceinline__ float allsum16(float x) {
    x = dpp_add<0xB1>(x);   // quad_perm xor1
    x = dpp_add<0x4E>(x);   // quad_perm xor2
    x = dpp_add<0x141>(x);  // row_half_mirror
    x = dpp_add<0x140>(x);  // row_mirror
    return x;
}
__device__ __forceinline__ int dpp_xor1_i(int v) {
    return __builtin_amdgcn_update_dpp(0, v, 0xB1, 0xF, 0xF, true);
}
__device__ __forceinline__ float rl(float x, int lane) {
    return __int_as_float(__builtin_amdgcn_readlane(__float_as_int(x), lane));
}

// ---------------------------------------------------------------------------
// Sequential RK4 scan, ONE wave.
//  layer1: per-lane unit j32, registers.
//  gather: h1 -> f16 pair pack (cvt+DPP+v_perm) -> 4x ds_bpermute -> A-frag.
//  layer2: 4x mfma_16x16x32_f16 (W2 hi+lo f16 split, 16 VGPRs).
//  layer3: TWO 16-lane butterflies (quad-row q reduces output o_q; 2nd does o4).
//  tail:   ONE packed exp2 + ONE packed rcp computes sinh(o0..o2), exp(o3,o4),
//          step_fn(s0), step_fn(s1), and next step's step_fn(-tm) args.
// ---------------------------------------------------------------------------
__global__ __launch_bounds__(64, 1) void scan_kernel(
    const float* __restrict__ inputs,   // (T,5)
    const float* __restrict__ lday,     // (T,)
    const float* __restrict__ W1, const float* __restrict__ b1,
    const float* __restrict__ W2, const float* __restrict__ b2,
    const float* __restrict__ W3, const float* __restrict__ b3,
    float* __restrict__ traj)           // (T,2)
{
    const int lane = threadIdx.x;
    const int col  = lane & 15;
    const int quad = lane >> 4;
    const int j32  = lane & 31;

    // layer-1 per-lane weights
    float w1c0 = W1[0 * HID + j32], w1c1 = W1[1 * HID + j32];
    float w1c2 = W1[2 * HID + j32], w1c3 = W1[3 * HID + j32];
    float b1j = b1[j32];
    PIN(w1c0); PIN(w1c1); PIN(w1c2); PIN(w1c3); PIN(b1j);

    // W2 as f16 hi/lo B-fragments: B[k][n], lane holds k=quad*8+jj, n=col(+16)
    f16x8 Bhi0, Blo0, Bhi1, Blo1;
#pragma unroll
    for (int jj = 0; jj < 8; ++jj) {
        float w0 = W2[(quad * 8 + jj) * HID + col];
        float w1v = W2[(quad * 8 + jj) * HID + col + 16];
        _Float16 h0 = (_Float16)w0, h1v = (_Float16)w1v;
        Bhi0[jj] = h0;  Blo0[jj] = (_Float16)(w0 - (float)h0);
        Bhi1[jj] = h1v; Blo1[jj] = (_Float16)(w1v - (float)h1v);
    }
    PIN(Bhi0); PIN(Blo0); PIN(Bhi1); PIN(Blo1);

    float b2a = b2[col], b2b = b2[col + 16];
    PIN(b2a); PIN(b2b);

    // layer-3 / tail per-lane constants
    float wqa = W3[col * 5 + quad];            // butterfly 1: quad-row q -> o_q
    float wqb = W3[(col + 16) * 5 + quad];
    float w4a = W3[col * 5 + 4];               // butterfly 2: o4
    float w4b = W3[(col + 16) * 5 + 4];
    float zb1 = b3[quad] * LOG2E;              // bias*log2e folded
    float zb4 = b3[4] * LOG2E;
    PIN(wqa); PIN(wqb); PIN(w4a); PIN(w4b); PIN(zb1); PIN(zb4);
    // one-hot float masks for the packed-exp lane layout
    float m1 = (col == 1) ? 1.f : 0.f;         // o4
    float m2 = (col == 2) ? 1.f : 0.f;         // sig10(s0)
    float m3 = (col == 3) ? 1.f : 0.f;         // sig10(s1)
    float m4 = (col == 4) ? 1.f : 0.f;         // next-step stm_mid
    float m5 = (col == 5) ? 1.f : 0.f;         // next-step stm_B
    float mo = (col == 0 || col >= 6) ? 1.f : 0.f;
    float sig1 = (col >= 2 && col <= 5) ? 1.f : 0.f;  // +1 before rcp (sigmoid)
    PIN(m1); PIN(m2); PIN(m3); PIN(m4); PIN(m5); PIN(mo); PIN(sig1);
    // v_perm selector: even lane -> (own.lo16 | nb.lo16<<16), odd -> swapped
    int psel = (lane & 1) ? 0x01000504 : 0x05040100;
    // bpermute byte addrs: pair m=4*quad+t lives in lane 2m -> addr 8m
    int bp0 = 32 * quad, bp1 = bp0 + 8, bp2 = bp0 + 16, bp3 = bp0 + 24;
    PIN(psel); PIN(bp0); PIN(bp1); PIN(bp2); PIN(bp3);

    double y0 = (double)inputs[0];
    double y1 = (double)inputs[1];
    float2* traj2 = (float2*)traj;
    if (lane == 0) traj2[0] = make_float2((float)y0, (float)y1);

    auto rhs = [&](float s0, float s1, float base, float stm, float ld,
                   float ztm_m, float ztm_b,
                   float& d0, float& d1, float& rout) {
        // off-chain: sigmoid args for the packed exp (state-dependent)
        float zs0 = s0 * NEG10LOG2E;
        float zs1 = s1 * NEG10LOG2E;
        float zoff = fmaf(zs0, m2, zs1 * m3) + fmaf(ztm_m, m4, ztm_b * m5);
        // layer 1
        float pre = fmaf(s1, w1c1, fmaf(s0, w1c0, base));
        float h1 = fast_tanh_clamp(pre);
        // pack adjacent-unit f16 pair, gather into A-layout via 4 bpermutes
        union { _Float16 h; unsigned short u; } cv; cv.h = (_Float16)h1;
        int own = (int)cv.u;
        int nb  = dpp_xor1_i(own);
        int pk  = __builtin_amdgcn_perm(nb, own, psel);
        int g0i = __builtin_amdgcn_ds_bpermute(bp0, pk);
        int g1i = __builtin_amdgcn_ds_bpermute(bp1, pk);
        int g2i = __builtin_amdgcn_ds_bpermute(bp2, pk);
        int g3i = __builtin_amdgcn_ds_bpermute(bp3, pk);
        union { int i[4]; f16x8 h; } au;
        au.i[0] = g0i; au.i[1] = g1i; au.i[2] = g2i; au.i[3] = g3i;
        f16x8 A = au.h;
        // layer 2: 4 independent MFMAs (hi+lo f16 decomposition of W2)
        f32x4 zz = {0.f, 0.f, 0.f, 0.f};
        f32x4 chi0 = __builtin_amdgcn_mfma_f32_16x16x32_f16(A, Bhi0, zz, 0, 0, 0);
        f32x4 clo0 = __builtin_amdgcn_mfma_f32_16x16x32_f16(A, Blo0, zz, 0, 0, 0);
        f32x4 chi1 = __builtin_amdgcn_mfma_f32_16x16x32_f16(A, Bhi1, zz, 0, 0, 0);
        f32x4 clo1 = __builtin_amdgcn_mfma_f32_16x16x32_f16(A, Blo1, zz, 0, 0, 0);
        float g0 = fast_tanh_nc((chi0[0] + clo0[0]) + b2a);   // unit col
        float g1 = fast_tanh_nc((chi1[0] + clo1[0]) + b2b);   // unit col+16
        // layer 3: two butterflies (quad-row q sums o_q; second sums o4)
        float c1 = fmaf(g0, wqa, g1 * wqb);
        float c4 = fmaf(g0, w4a, g1 * w4b);
        float s1r = allsum16(c1);
        float s4r = allsum16(c4);
        float z1 = fmaf(s1r, LOG2E, zb1);
        float z4 = fmaf(s4r, LOG2E, zb4);
        float zarg = fmaf(z1, mo, fmaf(z4, m1, zoff));
        // packed transcendental: one exp2, one rcp for the whole tail
        float u = fexp2(zarg);
        float v = u + sig1;       // +1 only on sigmoid lanes
        float r = frcp(v);
        float w = fmaf(0.5f, u, -0.5f * r);   // sinh on o-lanes
        float sh0 = rl(w, 0),  sh1 = rl(w, 16), sh2 = rl(w, 32);
        float e3  = rl(u, 48), e4  = rl(u, 1);
        float sg0 = rl(r, 2),  sg1 = rl(r, 3);
        // fluxes (uniform)
        float p_snow = fmaxf(sh0 * stm, 0.f);
        float p_rain = fmaxf(sh1, 0.f);
        float melt   = fmaxf(sg0 * sh2, 0.f);
        float etq    = sg1 * fmaf(e3, ld, e4);   // et + q
        d0 = p_snow - melt;
        d1 = (p_rain + melt) - etq;
        rout = r;   // lanes 4,5 hold next step's stm values (used after stage 4)
    };

    // pipelined stage inputs: A=step n, B=n+1, C=n+2 (raw prefetch)
    float pA = inputs[2],  tmA = inputs[3],  ldA = lday[0];
    float pB = inputs[7],  tmB = inputs[8],  ldB = lday[1];
    float pC = inputs[12], tmC = inputs[13], ldC = lday[2];
    float stmA = fast_sig10(-tmA);
    float stmB = fast_sig10(-tmB);
    float stmm = fast_sig10(-0.5f * (tmA + tmB));
    float baseA = fmaf(pA, w1c2, fmaf(tmA, w1c3, b1j));
    float baseB = fmaf(pB, w1c2, fmaf(tmB, w1c3, b1j));

    for (int n = 0; n < T_TOTAL - 1; ++n) {
        const float pm  = 0.5f * (pA + pB);
        const float tmm = 0.5f * (tmA + tmB);
        const float ldm = 0.5f * (ldA + ldB);
        const float basem = fmaf(pm, w1c2, fmaf(tmm, w1c3, b1j));
        // next step's step_fn(-tm) args, evaluated by the packed exp in-stage
        const float ztm_m = (0.5f * (tmB + tmC)) * POS10LOG2E;
        const float ztm_b = tmC * POS10LOG2E;

        const float fy0 = (float)y0, fy1 = (float)y1;
        float k10, k11, k20, k21, k30, k31, k40, k41, rd;
        rhs(fy0,                  fy1,                  baseA, stmA, ldA, ztm_m, ztm_b, k10, k11, rd);
        rhs(fmaf(0.5f, k10, fy0), fmaf(0.5f, k11, fy1), basem, stmm, ldm, ztm_m, ztm_b, k20, k21, rd);
        rhs(fmaf(0.5f, k20, fy0), fmaf(0.5f, k21, fy1), basem, stmm, ldm, ztm_m, ztm_b, k30, k31, rd);
        rhs(fy0 + k30,            fy1 + k31,            baseB, stmB, ldB, ztm_m, ztm_b, k40, k41, rd);
        const float stmm_n = rl(rd, 4);
        const float stmB_n = rl(rd, 5);

        const float s0sum = (k10 + 2.0f * k20) + (2.0f * k30 + k40);
        const float s1sum = (k11 + 2.0f * k21) + (2.0f * k31 + k41);
        y0 += (1.0 / 6.0) * (double)s0sum;
        y1 += (1.0 / 6.0) * (double)s1sum;

        if (lane == 0) traj2[n + 1] = make_float2((float)y0, (float)y1);

        // shift pipeline
        stmA = stmB; stmB = stmB_n; stmm = stmm_n;
        baseA = baseB;
        baseB = fmaf(pC, w1c2, fmaf(tmC, w1c3, b1j));
        pA = pB; tmA = tmB; ldA = ldB;
        pB = pC; tmB = tmC; ldB = ldC;
        const int np3 = (n + 3 < T_TOTAL) ? (n + 3) : (T_TOTAL - 1);
        pC = inputs[np3 * 5 + 2]; tmC = inputs[np3 * 5 + 3]; ldC = lday[np3];
    }
}

// ---------------------------------------------------------------------------
// Parallel readout: out[t] = mlp(relu(state), p, tm)[4]
// ---------------------------------------------------------------------------
__global__ __launch_bounds__(256) void out_kernel(
    const float* __restrict__ inputs,
    const float* __restrict__ traj,
    const float* __restrict__ W1, const float* __restrict__ b1,
    const float* __restrict__ W2, const float* __restrict__ b2,
    const float* __restrict__ W3, const float* __restrict__ b3,
    float* __restrict__ out)
{
    __shared__ float sW1[4 * HID];
    __shared__ float sb1[HID];
    __shared__ float sW2T[HID * HID];   // sW2T[j*HID+i] = W2[i][j]
    __shared__ float sb2[HID];
    __shared__ float sw3[HID];          // W3[:,4]
    for (int i = threadIdx.x; i < 4 * HID; i += 256) sW1[i] = W1[i];
    for (int i = threadIdx.x; i < HID; i += 256) {
        sb1[i] = b1[i]; sb2[i] = b2[i]; sw3[i] = W3[i * 5 + 4];
    }
    for (int idx = threadIdx.x; idx < HID * HID; idx += 256) {
        int jj = idx >> 5, ii = idx & 31;
        sW2T[idx] = W2[ii * HID + jj];
    }
    __syncthreads();

    int t = blockIdx.x * 256 + threadIdx.x;
    if (t >= T_TOTAL) return;

    float2 st = ((const float2*)traj)[t];
    float s0 = fmaxf(st.x, 0.0f);
    float s1 = fmaxf(st.y, 0.0f);
    float p  = inputs[t * 5 + 2];
    float tm = inputs[t * 5 + 3];

    float h1[HID];
#pragma unroll
    for (int jj = 0; jj < HID; ++jj) {
        float pre = fmaf(s0, sW1[jj], fmaf(s1, sW1[HID + jj],
                    fmaf(p, sW1[2 * HID + jj],
                    fmaf(tm, sW1[3 * HID + jj], sb1[jj]))));
        h1[jj] = fast_tanh_clamp(pre);
    }
    float o = b3[4];
#pragma unroll 4
    for (int jj = 0; jj < HID; ++jj) {
        float a0 = sb2[jj], a1 = 0.f, a2 = 0.f, a3 = 0.f;
#pragma unroll
        for (int ii = 0; ii < HID; ii += 4) {
            a0 = fmaf(h1[ii + 0], sW2T[jj * HID + ii + 0], a0);
            a1 = fmaf(h1[ii + 1], sW2T[jj * HID + ii + 1], a1);
            a2 = fmaf(h1[ii + 2], sW2T[jj * HID + ii + 2], a2);
            a3 = fmaf(h1[ii + 3], sW2T[jj * HID + ii + 3], a3);
        }
        o = fmaf(fast_tanh_nc((a0 + a1) + (a2 + a3)), sw3[jj], o);
    }
    out[t] = o;
}

extern "C" void kernel_launch(void* const* d_in, const int* in_sizes, int n_in,
                              void* d_out, int out_size, void* d_ws, size_t ws_size,
                              hipStream_t stream) {
    (void)in_sizes; (void)n_in; (void)out_size; (void)ws_size;
    const float* inputs = (const float*)d_in[0];
    const float* lday   = (const float*)d_in[1];
    const float* W1     = (const float*)d_in[2];
    const float* b1     = (const float*)d_in[3];
    const float* W2     = (const float*)d_in[4];
    const float* b2     = (const float*)d_in[5];
    const float* W3     = (const float*)d_in[6];
    const float* b3     = (const float*)d_in[7];
    float* out  = (float*)d_out;
    float* traj = (float*)d_ws;   // T*2 floats = 2 MB

    hipLaunchKernelGGL(scan_kernel, dim3(1), dim3(64), 0, stream,
                       inputs, lday, W1, b1, W2, b2, W3, b3, traj);
    hipLaunchKernelGGL(out_kernel, dim3((T_TOTAL + 255) / 256), dim3(256), 0, stream,
                       inputs, traj, W1, b1, W2, b2, W3, b3, out);
}